// Round 8
// baseline (172.163 us; speedup 1.0000x reference)
//
#include <hip/hip_runtime.h>

typedef unsigned short u16;
typedef unsigned char u8;
typedef unsigned int u32;
typedef float f32x4 __attribute__((ext_vector_type(4)));
typedef __bf16 bf16x8 __attribute__((ext_vector_type(8)));

#define SPB 6291456      // bytes per packed branch: B*N*C = 16*1024*384 (u8, 4 t-bits)

// ---- async global->LDS, 16B per lane, dest = wave-uniform base + lane*16 ----
__device__ __forceinline__ void gll16(const void* g, void* l) {
  __builtin_amdgcn_global_load_lds((const __attribute__((address_space(1))) void*)g,
                                   (__attribute__((address_space(3))) void*)l, 16, 0, 0);
}

// expand 8 packed spike-bytes (bit t) -> 8 bf16 {0,1}; perm+mul: (b0|b1<<16)*0x3F80
__device__ __forceinline__ uint4 expand8f(uint2 v, u32 t) {
  u32 a = (v.x >> t) & 0x01010101u;
  u32 b = (v.y >> t) & 0x01010101u;
  uint4 r;
  r.x = __builtin_amdgcn_perm(0u, a, 0x0C010C00u) * 0x3F80u;
  r.y = __builtin_amdgcn_perm(0u, a, 0x0C030C02u) * 0x3F80u;
  r.z = __builtin_amdgcn_perm(0u, b, 0x0C010C00u) * 0x3F80u;
  r.w = __builtin_amdgcn_perm(0u, b, 0x0C030C02u) * 0x3F80u;
  return r;
}

// ---------------- K0: weights -> bf16 (stacked q,k,v), BN params fused ----------------
__global__ __launch_bounds__(256) void k_convert(
    const float* __restrict__ qw, const float* __restrict__ kw,
    const float* __restrict__ vw, const float* __restrict__ pw,
    const float* __restrict__ qg, const float* __restrict__ qbt,
    const float* __restrict__ qm, const float* __restrict__ qv,
    const float* __restrict__ kg, const float* __restrict__ kbt,
    const float* __restrict__ km, const float* __restrict__ kv,
    const float* __restrict__ vg, const float* __restrict__ vbt,
    const float* __restrict__ vm, const float* __restrict__ vv,
    const float* __restrict__ pg, const float* __restrict__ pbt,
    const float* __restrict__ pm, const float* __restrict__ pv,
    const float* __restrict__ pbias,
    u16* __restrict__ Wstk, u16* __restrict__ Pw,
    float4* __restrict__ BNP, float4* __restrict__ PP) {
  int tid = blockIdx.x * 256 + threadIdx.x;
  if (tid < 442368) {               // Wstk[1152][384]
    int r = tid / 384, c = tid - r * 384;
    const float* src = (r < 384) ? qw : (r < 768) ? kw : vw;
    int rr = (r >= 768) ? r - 768 : (r >= 384) ? r - 384 : r;
    unsigned int u = __float_as_uint(src[rr * 384 + c]);
    u = (u + 0x7FFFu + ((u >> 16) & 1u)) >> 16;   // RNE to bf16
    Wstk[tid] = (u16)u;
  } else if (tid < 589824) {        // Pw[384][384]
    int i = tid - 442368;
    unsigned int u = __float_as_uint(pw[i]);
    u = (u + 0x7FFFu + ((u >> 16) & 1u)) >> 16;
    Pw[i] = (u16)u;
  } else if (tid < 590976) {        // BNP[1152] = {inv, mean, beta, -}
    int r = tid - 589824;
    int br = r / 384, ch = r - br * 384;
    const float* g  = (br == 0) ? qg  : (br == 1) ? kg  : vg;
    const float* bt = (br == 0) ? qbt : (br == 1) ? kbt : vbt;
    const float* m  = (br == 0) ? qm  : (br == 1) ? km  : vm;
    const float* va = (br == 0) ? qv  : (br == 1) ? kv  : vv;
    float inv = g[ch] / sqrtf(va[ch] + 1e-5f);
    BNP[r] = make_float4(inv, m[ch], bt[ch], 0.f);
  } else if (tid < 591360) {        // PP[384] = {inv, mean, beta, bias}
    int ch = tid - 590976;
    float inv = pg[ch] / sqrtf(pv[ch] + 1e-5f);
    PP[ch] = make_float4(inv, pm[ch], pbt[ch], pbias[ch]);
  }
}

// ---------------- K1: input LIF -> packed nibble xsb[(b*1024+n)*384 + c] --------------
__global__ __launch_bounds__(256) void k_lif_in(const float* __restrict__ x, u8* __restrict__ xsb) {
  const int nt = blockIdx.x, ct = blockIdx.y, b = blockIdx.z;
  const int tid = threadIdx.x;
  const int nj = tid & 63, cr = tid >> 6;
  const int c0 = ct * 64, n0 = nt * 64;
  __shared__ u32 nibs[64 * 65];     // [nj][c], +1-pad (u32) -> conflict-free
  float v[16];
  u32 nib[16];
  #pragma unroll
  for (int i = 0; i < 16; ++i) { v[i] = 0.f; nib[i] = 0u; }
  for (int t = 0; t < 4; ++t) {
    const float* xr = x + (((t * 16 + b) * 384 + c0 + cr) * 1024) + n0 + nj;
    #pragma unroll
    for (int it = 0; it < 16; ++it) {
      float xv = xr[it * 4096];
      float vv = v[it];
      float h = __fadd_rn(vv, __fmul_rn(__fsub_rn(xv, vv), 0.5f));  // v + (x-v)/2, exact order
      bool s = h >= 1.f;
      v[it] = s ? 0.f : h;
      nib[it] |= (s ? 1u : 0u) << t;
    }
  }
  #pragma unroll
  for (int it = 0; it < 16; ++it) nibs[nj * 65 + cr + it * 4] = nib[it];
  __syncthreads();
  const int n = tid >> 2, ch = tid & 3;
  u32 w0[4];
  #pragma unroll
  for (int q = 0; q < 4; ++q) {
    u32 acc = 0;
    #pragma unroll
    for (int i = 0; i < 4; ++i)
      acc |= (nibs[n * 65 + ch * 16 + q * 4 + i] & 0xFu) << (8 * i);
    w0[q] = acc;
  }
  *(uint4*)(xsb + ((size_t)(b * 1024 + n0 + n)) * 384 + c0 + ch * 16) =
      make_uint4(w0[0], w0[1], w0[2], w0[3]);
}

// ======================================================================================
// Pipelined GEMM core v4.1 (3-plane collapse, de-spilled): per block, X tile 256 j x
// 384 k staged ONCE, multiplied against 3 W planes of 128 c rows (q/k/v, or Pw panels).
// BK=32, 512 thr, 8 waves; per wave per K-tile: 48 MFMA, 16 ds_read.
// __launch_bounds__(512,1): full 512-reg/wave budget -> 192-reg acc fits, NO spill
// (R7's (512,2) capped at 256 and spilled 120 MB/dispatch to scratch).
// Buffer (40KB = 20480 u16): [W 3x128x32 @0,4096,8192][X 256x32 @12288].
// 3 buffers (120KB+PRM) -> 1 block/CU. 2 tiles in flight, counted vmcnt(5), 1 barrier/it.
// Chunk XOR swizzle identical to v2/v3 (verified 0 bank conflicts).
// ======================================================================================
#define BUFU16 20480

#define GISSUE(kt) do { \
    u16* wb_ = &lds[((kt) % 3) * BUFU16 + wst]; \
    gll16(Wp0 + (kt) * 32, wb_); \
    gll16(Wp1 + (kt) * 32, wb_ + 4096); \
    gll16(Wp2 + (kt) * 32, wb_ + 8192); \
    xr0[(kt) % 3] = *(const uint2*)(Xb0 + (kt) * 32); \
    xr1[(kt) % 3] = *(const uint2*)(Xb1 + (kt) * 32); \
  } while (0)

#define GWRITE(kt) do { \
    *(uint4*)&lds[((kt) % 3) * BUFU16 + 12288 + tid * 8] = expand8f(xr0[(kt) % 3], t_row); \
    *(uint4*)&lds[((kt) % 3) * BUFU16 + 12288 + 4096 + tid * 8] = expand8f(xr1[(kt) % 3], t_row); \
  } while (0)

#define MFMA4(accA, p) do { \
    _Pragma("unroll") \
    for (int ci = 0; ci < 4; ++ci) { \
      bf16x8 bw_ = *(const bf16x8*)&lb_[(p) * 4096 + (wcg * 64 + ci * 16 + l15) * 32 + swoff]; \
      _Pragma("unroll") \
      for (int ji = 0; ji < 4; ++ji) \
        accA[ji][ci] = __builtin_amdgcn_mfma_f32_16x16x32_bf16(ax[ji], bw_, accA[ji][ci], 0, 0, 0); \
    } \
  } while (0)

#define COMPUTE3(bufi) do { \
    const u16* lb_ = &lds[(bufi) * BUFU16]; \
    bf16x8 ax[4]; \
    _Pragma("unroll") \
    for (int ji = 0; ji < 4; ++ji) \
      ax[ji] = *(const bf16x8*)&lb_[12288 + (wjg * 64 + ji * 16 + l15) * 32 + swoff]; \
    __builtin_amdgcn_s_setprio(1); \
    MFMA4(acc0, 0); MFMA4(acc1, 1); MFMA4(acc2, 2); \
    __builtin_amdgcn_s_setprio(0); \
  } while (0)

#define GSTEP(t, VN, TAIL) do { \
    asm volatile("s_waitcnt vmcnt(" #VN ")" ::: "memory"); \
    GWRITE(t); \
    asm volatile("s_waitcnt lgkmcnt(0)" ::: "memory"); \
    __builtin_amdgcn_s_barrier(); \
    asm volatile("" ::: "memory"); \
    TAIL; \
    COMPUTE3((t) % 3); \
  } while (0)

#define GEMM_PIPELINE3() do { \
    GISSUE(0); GISSUE(1); \
    GSTEP(0, 5, GISSUE(2)); \
    GSTEP(1, 5, GISSUE(3)); \
    GSTEP(2, 5, GISSUE(4)); \
    GSTEP(3, 5, GISSUE(5)); \
    GSTEP(4, 5, GISSUE(6)); \
    GSTEP(5, 5, GISSUE(7)); \
    GSTEP(6, 5, GISSUE(8)); \
    GSTEP(7, 5, GISSUE(9)); \
    GSTEP(8, 5, GISSUE(10)); \
    GSTEP(9, 5, GISSUE(11)); \
    GSTEP(10, 5, ); \
    GSTEP(11, 0, ); \
  } while (0)

#define GEMM_SETUP() \
  const int tid = threadIdx.x; \
  const int w = tid >> 6, l = tid & 63; \
  const int wjg = w >> 1, wcg = w & 1; \
  const int l15 = tid & 15, g = l >> 4; \
  const int swoff = (g ^ ((l15 >> 1) & 3)) * 8; \
  const int wst = w * 512; \
  const int row = tid >> 2; \
  const u32 t_row = (u32)(row & 3); \
  const int sch = (l & 3) ^ ((l >> 3) & 3); \
  uint2 xr0[3], xr1[3]; \
  f32x4 acc0[4][4], acc1[4][4], acc2[4][4]; \
  { const f32x4 zero_ = {0.f, 0.f, 0.f, 0.f}; \
    _Pragma("unroll") \
    for (int ji = 0; ji < 4; ++ji) \
      _Pragma("unroll") \
      for (int ci = 0; ci < 4; ++ci) { acc0[ji][ci] = zero_; acc1[ji][ci] = zero_; acc2[ji][ci] = zero_; } }

// ---------------- K2: qkv GEMM, 3 branches per block + BN + LIF -> sp u8 nibbles ------
__global__ __launch_bounds__(512, 1) void k_qkv(
    const u16* __restrict__ Wstk, const u8* __restrict__ xsb,
    const float4* __restrict__ BNP, u8* __restrict__ sp) {
  const int jt = blockIdx.x, cb = blockIdx.y, b = blockIdx.z;
  __shared__ u16 lds[61440];                      // 3 x 40KB buffers
  __shared__ float4 PRM[384];

  GEMM_SETUP();

  if (tid < 384) PRM[tid] = BNP[(tid >> 7) * 384 + cb * 128 + (tid & 127)];
  asm volatile("s_waitcnt vmcnt(0)" ::: "memory");   // clean vmcnt before counted pipeline

  const u16* Wp0 = Wstk + (size_t)(cb * 128 + row) * 384 + sch * 8;   // branch q rows
  const u16* Wp1 = Wp0 + 147456;                                      // + 384 rows: k
  const u16* Wp2 = Wp1 + 147456;                                      // + 384 rows: v
  const u8* Xb0 = xsb + ((size_t)(b * 1024 + jt * 64 + (row >> 2))) * 384 + sch * 8;
  const u8* Xb1 = Xb0 + 32 * 384;

  GEMM_PIPELINE3();

  // epilogue: BN + 4-step LIF (acc regs = t), pack 4 spike bits -> one u8, per branch
  const int n_base = b * 1024 + jt * 64 + wjg * 16 + g;
#define QKV_EPI(accA, br) do { \
    u8* spW = sp + (size_t)(br) * SPB; \
    _Pragma("unroll") \
    for (int ci = 0; ci < 4; ++ci) { \
      const int c_loc = wcg * 64 + ci * 16 + l15; \
      float4 pr = PRM[(br) * 128 + c_loc]; \
      _Pragma("unroll") \
      for (int ji = 0; ji < 4; ++ji) { \
        f32x4 a = accA[ji][ci]; \
        u32 bits = 0; \
        float vv = 0.f; \
        _Pragma("unroll") \
        for (int t = 0; t < 4; ++t) { \
          float z = __fadd_rn(__fmul_rn(__fsub_rn(a[t], pr.y), pr.x), pr.z); \
          float h = __fadd_rn(vv, __fmul_rn(__fsub_rn(z, vv), 0.5f)); \
          bool s = h >= 1.f; \
          vv = s ? 0.f : h; \
          bits |= (s ? 1u : 0u) << t; \
        } \
        spW[(size_t)(n_base + ji * 4) * 384 + cb * 128 + c_loc] = (u8)bits; \
      } \
    } \
  } while (0)
  QKV_EPI(acc0, 0);
  QKV_EPI(acc1, 1);
  QKV_EPI(acc2, 2);
#undef QKV_EPI
}

// ---------------- K3: attn = sum_ch(k&v) per head, LIF(0.5) -> xpb = q & mask ---------
__global__ __launch_bounds__(256) void k_attn(const u8* __restrict__ sp, u8* __restrict__ xpb) {
  const int gw = blockIdx.x * 4 + (threadIdx.x >> 6);
  const int l = threadIdx.x & 63;
  const int b = gw >> 10, n = gw & 1023;
  const u8* qB = sp;
  const u8* kB = sp + SPB;
  const u8* vB = sp + 2 * SPB;
  const int base = (b * 1024 + n) * 384 + l * 6;   // byte index; lane covers 6 channels
  u16 qu[3], ku[3], vu[3];
  #pragma unroll
  for (int i = 0; i < 3; ++i) {
    qu[i] = *(const u16*)(qB + base + 2 * i);
    ku[i] = *(const u16*)(kB + base + 2 * i);
    vu[i] = *(const u16*)(vB + base + 2 * i);
  }
  u32 s = 0;                        // 4 per-t byte sums packed in a u32
  #pragma unroll
  for (int i = 0; i < 3; ++i) {
    u32 a = (u32)(ku[i] & vu[i]);
    #pragma unroll
    for (int t = 0; t < 4; ++t) {
      u32 x = (a >> t) & 0x0101u;
      s += ((x + (x >> 8)) & 3u) << (8 * t);
    }
  }
  s += __shfl_xor(s, 1);
  s += __shfl_xor(s, 2);
  s += __shfl_xor(s, 4);            // 8 lanes == one 48-channel head; bytes <= 48
  float v = 0.f;
  u32 m8 = 0;
  #pragma unroll
  for (int t = 0; t < 4; ++t) {
    float attn = (float)((s >> (8 * t)) & 0xFFu);
    float h = __fadd_rn(v, __fmul_rn(__fsub_rn(attn, v), 0.5f));
    bool sk = h >= 0.5f;
    v = sk ? 0.f : h;
    m8 |= (sk ? 1u : 0u) << t;
  }
  const u16 mm = (u16)(m8 * 0x0101u);
  u16* dst = (u16*)(xpb + base);
  #pragma unroll
  for (int i = 0; i < 3; ++i) dst[i] = qu[i] & mm;
}

// ---------------- K4: P GEMM (384 c per block) + bias + BN -> out fp32 ----------------
__global__ __launch_bounds__(512, 1) void k_proj(
    const u16* __restrict__ Pw, const u8* __restrict__ xpb,
    const float4* __restrict__ PP, float* __restrict__ out) {
  const int jt = blockIdx.x, b = blockIdx.z;
  __shared__ u16 lds[61440];
  __shared__ float4 PRM[384];

  GEMM_SETUP();

  if (tid < 384) PRM[tid] = PP[tid];
  asm volatile("s_waitcnt vmcnt(0)" ::: "memory");

  const u16* Wp0 = Pw + (size_t)row * 384 + sch * 8;   // c rows 0-127
  const u16* Wp1 = Wp0 + 49152;                        // 128-255
  const u16* Wp2 = Wp1 + 49152;                        // 256-383
  const u8* Xb0 = xpb + ((size_t)(b * 1024 + jt * 64 + (row >> 2))) * 384 + sch * 8;
  const u8* Xb1 = Xb0 + 32 * 384;

  GEMM_PIPELINE3();

  __syncthreads();                                 // all waves done with buffers
  float* scr = (float*)lds;                        // 128 x 68-padded f32 tile (34.8KB)
  const int n0im = jt * 64;
#define PROJ_EPI(accA, p) \
  _Pragma("unroll") \
  for (int t = 0; t < 4; ++t) { \
    _Pragma("unroll") \
    for (int ci = 0; ci < 4; ++ci) { \
      const int c_loc = wcg * 64 + ci * 16 + l15; \
      float4 pr = PRM[(p) * 128 + c_loc]; \
      _Pragma("unroll") \
      for (int ji = 0; ji < 4; ++ji) { \
        const int n_loc = wjg * 16 + ji * 4 + g; \
        float zz = __fadd_rn(accA[ji][ci][t], pr.w); \
        zz = __fadd_rn(__fmul_rn(__fsub_rn(zz, pr.y), pr.x), pr.z); \
        scr[c_loc * 68 + n_loc] = zz; \
      } \
    } \
    __syncthreads(); \
    _Pragma("unroll") \
    for (int it = 0; it < 4; ++it) { \
      int slot = tid + it * 512; \
      int c = slot >> 4, li = slot & 15; \
      float4 val = *(const float4*)&scr[c * 68 + li * 4]; \
      *(float4*)&out[(((size_t)(t * 16 + b) * 384) + (p) * 128 + c) * 1024 + n0im + li * 4] = val; \
    } \
    __syncthreads(); \
  }
  PROJ_EPI(acc0, 0)
  PROJ_EPI(acc1, 1)
  PROJ_EPI(acc2, 2)
#undef PROJ_EPI
}

extern "C" void kernel_launch(void* const* d_in, const int* in_sizes, int n_in,
                              void* d_out, int out_size, void* d_ws, size_t ws_size,
                              hipStream_t stream) {
  (void)in_sizes; (void)n_in; (void)out_size; (void)ws_size;
  const float* x   = (const float*)d_in[0];
  const float* qw  = (const float*)d_in[1];
  const float* qg  = (const float*)d_in[2];
  const float* qbt = (const float*)d_in[3];
  const float* qm  = (const float*)d_in[4];
  const float* qv  = (const float*)d_in[5];
  const float* kw  = (const float*)d_in[6];
  const float* kg  = (const float*)d_in[7];
  const float* kbt = (const float*)d_in[8];
  const float* km  = (const float*)d_in[9];
  const float* kv  = (const float*)d_in[10];
  const float* vw  = (const float*)d_in[11];
  const float* vg  = (const float*)d_in[12];
  const float* vbt = (const float*)d_in[13];
  const float* vm  = (const float*)d_in[14];
  const float* vv  = (const float*)d_in[15];
  const float* pw  = (const float*)d_in[16];
  const float* pg  = (const float*)d_in[17];
  const float* pbt = (const float*)d_in[18];
  const float* pm  = (const float*)d_in[19];
  const float* pv  = (const float*)d_in[20];
  const float* pbias = (const float*)d_in[21];

  char* ws = (char*)d_ws;
  u8*  xsb   = (u8*)ws;                     // input spikes, packed nibbles (6.3 MB)
  u8*  sp    = (u8*)(ws + 6291456);         // q,k,v spike nibbles (3 x 6.3 MB)
  u8*  xpb   = (u8*)(ws + 25165824);        // q&attn spikes, packed nibbles (6.3 MB)
  u16* Wstk  = (u16*)(ws + 31457280);       // [1152][384] bf16
  u16* Pw    = (u16*)(ws + 32342016);       // [384][384] bf16
  float4* BNP = (float4*)(ws + 32636928);   // [1152]
  float4* PP  = (float4*)(ws + 32655360);   // [384]

  k_convert<<<2310, 256, 0, stream>>>(qw, kw, vw, pw, qg, qbt, qm, qv, kg, kbt, km, kv,
                                      vg, vbt, vm, vv, pg, pbt, pm, pv, pbias,
                                      Wstk, Pw, BNP, PP);
  k_lif_in<<<dim3(16, 6, 16), 256, 0, stream>>>(x, xsb);
  k_qkv<<<dim3(16, 3, 16), 512, 0, stream>>>(Wstk, xsb, BNP, sp);
  k_attn<<<4096, 256, 0, stream>>>(sp, xpb);
  k_proj<<<dim3(16, 1, 16), 512, 0, stream>>>(Pw, xpb, PP, (float*)d_out);
}

// Round 9
// 123.053 us; speedup vs baseline: 1.3991x; 1.3991x over previous
//
#include <hip/hip_runtime.h>

typedef unsigned short u16;
typedef unsigned char u8;
typedef unsigned int u32;
typedef float f32x4 __attribute__((ext_vector_type(4)));
typedef __bf16 bf16x8 __attribute__((ext_vector_type(8)));

#define SPB 6291456      // bytes per packed branch: B*N*C = 16*1024*384 (u8, 4 t-bits)

// ---- async global->LDS, 16B per lane, dest = wave-uniform base + lane*16 ----
__device__ __forceinline__ void gll16(const void* g, void* l) {
  __builtin_amdgcn_global_load_lds((const __attribute__((address_space(1))) void*)g,
                                   (__attribute__((address_space(3))) void*)l, 16, 0, 0);
}

// expand 8 packed spike-bytes (bit t) -> 8 bf16 {0,1}; perm+mul: (b0|b1<<16)*0x3F80
__device__ __forceinline__ uint4 expand8f(uint2 v, u32 t) {
  u32 a = (v.x >> t) & 0x01010101u;
  u32 b = (v.y >> t) & 0x01010101u;
  uint4 r;
  r.x = __builtin_amdgcn_perm(0u, a, 0x0C010C00u) * 0x3F80u;
  r.y = __builtin_amdgcn_perm(0u, a, 0x0C030C02u) * 0x3F80u;
  r.z = __builtin_amdgcn_perm(0u, b, 0x0C010C00u) * 0x3F80u;
  r.w = __builtin_amdgcn_perm(0u, b, 0x0C030C02u) * 0x3F80u;
  return r;
}

// ---------------- K0: weights -> bf16 (stacked q,k,v), BN params fused ----------------
__global__ __launch_bounds__(256) void k_convert(
    const float* __restrict__ qw, const float* __restrict__ kw,
    const float* __restrict__ vw, const float* __restrict__ pw,
    const float* __restrict__ qg, const float* __restrict__ qbt,
    const float* __restrict__ qm, const float* __restrict__ qv,
    const float* __restrict__ kg, const float* __restrict__ kbt,
    const float* __restrict__ km, const float* __restrict__ kv,
    const float* __restrict__ vg, const float* __restrict__ vbt,
    const float* __restrict__ vm, const float* __restrict__ vv,
    const float* __restrict__ pg, const float* __restrict__ pbt,
    const float* __restrict__ pm, const float* __restrict__ pv,
    const float* __restrict__ pbias,
    u16* __restrict__ Wstk, u16* __restrict__ Pw,
    float4* __restrict__ BNP, float4* __restrict__ PP) {
  int tid = blockIdx.x * 256 + threadIdx.x;
  if (tid < 442368) {               // Wstk[1152][384]
    int r = tid / 384, c = tid - r * 384;
    const float* src = (r < 384) ? qw : (r < 768) ? kw : vw;
    int rr = (r >= 768) ? r - 768 : (r >= 384) ? r - 384 : r;
    unsigned int u = __float_as_uint(src[rr * 384 + c]);
    u = (u + 0x7FFFu + ((u >> 16) & 1u)) >> 16;   // RNE to bf16
    Wstk[tid] = (u16)u;
  } else if (tid < 589824) {        // Pw[384][384]
    int i = tid - 442368;
    unsigned int u = __float_as_uint(pw[i]);
    u = (u + 0x7FFFu + ((u >> 16) & 1u)) >> 16;
    Pw[i] = (u16)u;
  } else if (tid < 590976) {        // BNP[1152] = {inv, mean, beta, -}
    int r = tid - 589824;
    int br = r / 384, ch = r - br * 384;
    const float* g  = (br == 0) ? qg  : (br == 1) ? kg  : vg;
    const float* bt = (br == 0) ? qbt : (br == 1) ? kbt : vbt;
    const float* m  = (br == 0) ? qm  : (br == 1) ? km  : vm;
    const float* va = (br == 0) ? qv  : (br == 1) ? kv  : vv;
    float inv = g[ch] / sqrtf(va[ch] + 1e-5f);
    BNP[r] = make_float4(inv, m[ch], bt[ch], 0.f);
  } else if (tid < 591360) {        // PP[384] = {inv, mean, beta, bias}
    int ch = tid - 590976;
    float inv = pg[ch] / sqrtf(pv[ch] + 1e-5f);
    PP[ch] = make_float4(inv, pm[ch], pbt[ch], pbias[ch]);
  }
}

// ---------------- K1: input LIF -> packed nibble xsb[(b*1024+n)*384 + c] --------------
__global__ __launch_bounds__(256) void k_lif_in(const float* __restrict__ x, u8* __restrict__ xsb) {
  const int nt = blockIdx.x, ct = blockIdx.y, b = blockIdx.z;
  const int tid = threadIdx.x;
  const int nj = tid & 63, cr = tid >> 6;
  const int c0 = ct * 64, n0 = nt * 64;
  __shared__ u32 nibs[64 * 65];     // [nj][c], +1-pad (u32) -> conflict-free
  float v[16];
  u32 nib[16];
  #pragma unroll
  for (int i = 0; i < 16; ++i) { v[i] = 0.f; nib[i] = 0u; }
  for (int t = 0; t < 4; ++t) {
    const float* xr = x + (((t * 16 + b) * 384 + c0 + cr) * 1024) + n0 + nj;
    #pragma unroll
    for (int it = 0; it < 16; ++it) {
      float xv = xr[it * 4096];
      float vv = v[it];
      float h = __fadd_rn(vv, __fmul_rn(__fsub_rn(xv, vv), 0.5f));  // v + (x-v)/2, exact order
      bool s = h >= 1.f;
      v[it] = s ? 0.f : h;
      nib[it] |= (s ? 1u : 0u) << t;
    }
  }
  #pragma unroll
  for (int it = 0; it < 16; ++it) nibs[nj * 65 + cr + it * 4] = nib[it];
  __syncthreads();
  const int n = tid >> 2, ch = tid & 3;
  u32 w0[4];
  #pragma unroll
  for (int q = 0; q < 4; ++q) {
    u32 acc = 0;
    #pragma unroll
    for (int i = 0; i < 4; ++i)
      acc |= (nibs[n * 65 + ch * 16 + q * 4 + i] & 0xFu) << (8 * i);
    w0[q] = acc;
  }
  *(uint4*)(xsb + ((size_t)(b * 1024 + n0 + n)) * 384 + c0 + ch * 16) =
      make_uint4(w0[0], w0[1], w0[2], w0[3]);
}

// ======================================================================================
// GEMM core v5: per block, BM=128 c (one W panel), BN=256 j (64 n x 4 t), K=384 full.
// X stays PACKED in LDS for the whole K: [64 n][416B-padded row] = 26 KB, staged once
// (reg->ds_write), expanded to bf16 ON READ (ds_read_b64 4-lane-broadcast + v_perm).
// X-read bank map: addr mod 128 = d*32 + g*8 (d = l15>>2) -> 16 distinct slots, 0 conflicts.
// Only W is pipelined: 6 x 8KB buffers, 1 gll16/thread/tile, 5 tiles in flight,
// counted vmcnt(4), raw barrier per iter. LDS total 75776 B -> 2 blocks/CU, 4 waves/SIMD.
// Per wave per K-tile: 16 MFMA (~310cy/SIMD at 4 waves) vs ~300cy LDS -> balanced.
// W chunk XOR swizzle identical to v2/v3 (verified 0 bank conflicts).
// ======================================================================================
#define XLDS_U16 13312                 // 26624 B X region (64 rows x 416 B)
#define WSLOT_U16 4096                 // 8 KB per W buffer slot

#define GISSUE(kt) gll16(Wp + (kt) * 32, &lds[XLDS_U16 + ((kt) % 6) * WSLOT_U16 + wst])

#define SYNCP(n) do { \
    asm volatile("s_waitcnt vmcnt(" #n ")" ::: "memory"); \
    __builtin_amdgcn_s_barrier(); \
    asm volatile("" ::: "memory"); \
  } while (0)

#define COMPUTE(kt) do { \
    const u8* xb_ = (const u8*)lds; \
    const u16* wb_ = &lds[XLDS_U16 + ((kt) % 6) * WSLOT_U16]; \
    bf16x8 ax[4]; \
    _Pragma("unroll") \
    for (int ji = 0; ji < 4; ++ji) { \
      uint2 xr_ = *(const uint2*)(xb_ + (wjg * 16 + ji * 4 + d4) * 416 + (kt) * 32 + g8); \
      uint4 e_ = expand8f(xr_, t_lane); \
      ax[ji] = *(bf16x8*)&e_; \
    } \
    __builtin_amdgcn_s_setprio(1); \
    _Pragma("unroll") \
    for (int ci = 0; ci < 4; ++ci) { \
      bf16x8 bw_ = *(const bf16x8*)&wb_[(wcg * 64 + ci * 16 + l15) * 32 + swoff]; \
      _Pragma("unroll") \
      for (int ji = 0; ji < 4; ++ji) \
        acc[ji][ci] = __builtin_amdgcn_mfma_f32_16x16x32_bf16(ax[ji], bw_, acc[ji][ci], 0, 0, 0); \
    } \
    __builtin_amdgcn_s_setprio(0); \
  } while (0)

#define GEMM_PIPELINE() do { \
    GISSUE(0); GISSUE(1); GISSUE(2); GISSUE(3); GISSUE(4); \
    SYNCP(4); GISSUE(5);  COMPUTE(0); \
    SYNCP(4); GISSUE(6);  COMPUTE(1); \
    SYNCP(4); GISSUE(7);  COMPUTE(2); \
    SYNCP(4); GISSUE(8);  COMPUTE(3); \
    SYNCP(4); GISSUE(9);  COMPUTE(4); \
    SYNCP(4); GISSUE(10); COMPUTE(5); \
    SYNCP(4); GISSUE(11); COMPUTE(6); \
    SYNCP(4); COMPUTE(7); \
    SYNCP(3); COMPUTE(8); \
    SYNCP(2); COMPUTE(9); \
    SYNCP(1); COMPUTE(10); \
    SYNCP(0); COMPUTE(11); \
  } while (0)

// stage packed X strip (64 n x 384 B) into padded LDS rows (416 B), then sync
#define XSTAGE(XSRC) do { \
    const int xn_ = tid >> 3, xcp_ = tid & 7; \
    const u8* xs_ = (XSRC) + (size_t)(b * 1024 + jt * 64 + xn_) * 384 + xcp_ * 48; \
    u8* xd_ = (u8*)lds + xn_ * 416 + xcp_ * 48; \
    uint4 v0_ = *(const uint4*)(xs_); \
    uint4 v1_ = *(const uint4*)(xs_ + 16); \
    uint4 v2_ = *(const uint4*)(xs_ + 32); \
    *(uint4*)(xd_) = v0_; *(uint4*)(xd_ + 16) = v1_; *(uint4*)(xd_ + 32) = v2_; \
    __syncthreads(); \
  } while (0)

#define GEMM_SETUP() \
  const int tid = threadIdx.x; \
  const int w = tid >> 6, l = tid & 63; \
  const int wjg = w >> 1, wcg = w & 1; \
  const int l15 = tid & 15, g = l >> 4; \
  const int swoff = (g ^ ((l15 >> 1) & 3)) * 8; \
  const int wst = w * 512; \
  const int d4 = l15 >> 2, g8 = g * 8; \
  const u32 t_lane = (u32)(l15 & 3); \
  const int sch = (l & 3) ^ ((l >> 3) & 3); \
  f32x4 acc[4][4]; \
  { const f32x4 zero_ = {0.f, 0.f, 0.f, 0.f}; \
    _Pragma("unroll") \
    for (int ji = 0; ji < 4; ++ji) \
      _Pragma("unroll") \
      for (int ci = 0; ci < 4; ++ci) acc[ji][ci] = zero_; }

// ---------------- K2: qkv GEMM (one branch-panel per block) + BN + LIF -> sp nibbles --
__global__ __launch_bounds__(512, 4) void k_qkv(
    const u16* __restrict__ Wstk, const u8* __restrict__ xsb,
    const float4* __restrict__ BNP, u8* __restrict__ sp) {
  const int jt = blockIdx.x, mt = blockIdx.y, b = blockIdx.z;
  __shared__ u16 lds[37888];                      // 26624B X + 6x8KB W = 75776 B

  GEMM_SETUP();
  XSTAGE(xsb);

  const int m0 = mt * 128;                        // == (mt/3)*384 + (mt%3)*128 in Wstk
  const u16* Wp = Wstk + (size_t)(m0 + w * 16 + (l >> 2)) * 384 + sch * 8;

  GEMM_PIPELINE();

  // epilogue: BN + 4-step LIF (acc regs = t), pack 4 spike bits -> one u8
  const int br = mt / 3;
  const int cb = (mt - br * 3) * 128;
  const int n_base = b * 1024 + jt * 64 + wjg * 16 + g;
  u8* spW = sp + (size_t)br * SPB;
  #pragma unroll
  for (int ci = 0; ci < 4; ++ci) {
    const int c_loc = wcg * 64 + ci * 16 + l15;
    float4 pr = BNP[br * 384 + cb + c_loc];       // direct L2 load (PRM LDS removed)
    #pragma unroll
    for (int ji = 0; ji < 4; ++ji) {
      f32x4 a = acc[ji][ci];
      u32 bits = 0;
      float vv = 0.f;
      #pragma unroll
      for (int t = 0; t < 4; ++t) {
        float z = __fadd_rn(__fmul_rn(__fsub_rn(a[t], pr.y), pr.x), pr.z);  // BN, ref order
        float h = __fadd_rn(vv, __fmul_rn(__fsub_rn(z, vv), 0.5f));          // LIF step
        bool s = h >= 1.f;
        vv = s ? 0.f : h;
        bits |= (s ? 1u : 0u) << t;
      }
      spW[(size_t)(n_base + ji * 4) * 384 + cb + c_loc] = (u8)bits;
    }
  }
}

// ---------------- K3: attn = sum_ch(k&v) per head, LIF(0.5) -> xpb = q & mask ---------
__global__ __launch_bounds__(256) void k_attn(const u8* __restrict__ sp, u8* __restrict__ xpb) {
  const int gw = blockIdx.x * 4 + (threadIdx.x >> 6);
  const int l = threadIdx.x & 63;
  const int b = gw >> 10, n = gw & 1023;
  const u8* qB = sp;
  const u8* kB = sp + SPB;
  const u8* vB = sp + 2 * SPB;
  const int base = (b * 1024 + n) * 384 + l * 6;   // byte index; lane covers 6 channels
  u16 qu[3], ku[3], vu[3];
  #pragma unroll
  for (int i = 0; i < 3; ++i) {
    qu[i] = *(const u16*)(qB + base + 2 * i);
    ku[i] = *(const u16*)(kB + base + 2 * i);
    vu[i] = *(const u16*)(vB + base + 2 * i);
  }
  u32 s = 0;                        // 4 per-t byte sums packed in a u32
  #pragma unroll
  for (int i = 0; i < 3; ++i) {
    u32 a = (u32)(ku[i] & vu[i]);
    #pragma unroll
    for (int t = 0; t < 4; ++t) {
      u32 x = (a >> t) & 0x0101u;
      s += ((x + (x >> 8)) & 3u) << (8 * t);
    }
  }
  s += __shfl_xor(s, 1);
  s += __shfl_xor(s, 2);
  s += __shfl_xor(s, 4);            // 8 lanes == one 48-channel head; bytes <= 48
  float v = 0.f;
  u32 m8 = 0;
  #pragma unroll
  for (int t = 0; t < 4; ++t) {
    float attn = (float)((s >> (8 * t)) & 0xFFu);
    float h = __fadd_rn(v, __fmul_rn(__fsub_rn(attn, v), 0.5f));
    bool sk = h >= 0.5f;
    v = sk ? 0.f : h;
    m8 |= (sk ? 1u : 0u) << t;
  }
  const u16 mm = (u16)(m8 * 0x0101u);
  u16* dst = (u16*)(xpb + base);
  #pragma unroll
  for (int i = 0; i < 3; ++i) dst[i] = qu[i] & mm;
}

// ---------------- K4: P GEMM (one 128-c panel per block) + bias + BN -> out fp32 ------
__global__ __launch_bounds__(512, 4) void k_proj(
    const u16* __restrict__ Pw, const u8* __restrict__ xpb,
    const float4* __restrict__ PP, float* __restrict__ out) {
  const int jt = blockIdx.x, mt = blockIdx.y, b = blockIdx.z;
  __shared__ u16 lds[37888];

  GEMM_SETUP();
  XSTAGE(xpb);

  const int m0 = mt * 128;
  const u16* Wp = Pw + (size_t)(m0 + w * 16 + (l >> 2)) * 384 + sch * 8;

  GEMM_PIPELINE();

  __syncthreads();                                 // all waves done with LDS buffers
  float* scr = (float*)lds;                        // 128 x 68-padded f32 tile (34.8 KB)
  const int n0im = jt * 64;
  float4 prc[4];
  #pragma unroll
  for (int ci = 0; ci < 4; ++ci) prc[ci] = PP[m0 + wcg * 64 + ci * 16 + l15];

  #pragma unroll
  for (int t = 0; t < 4; ++t) {
    #pragma unroll
    for (int ci = 0; ci < 4; ++ci) {
      const int c_loc = wcg * 64 + ci * 16 + l15;
      float4 pr = prc[ci];
      #pragma unroll
      for (int ji = 0; ji < 4; ++ji) {
        const int n_loc = wjg * 16 + ji * 4 + g;
        float zz = __fadd_rn(acc[ji][ci][t], pr.w);                        // + bias
        zz = __fadd_rn(__fmul_rn(__fsub_rn(zz, pr.y), pr.x), pr.z);        // BN, ref order
        scr[c_loc * 68 + n_loc] = zz;
      }
    }
    __syncthreads();
    #pragma unroll
    for (int it = 0; it < 4; ++it) {
      int slot = tid + it * 512;                   // 2048 slots = 128 rows x 16 float4
      int c = slot >> 4, li = slot & 15;
      float4 val = *(const float4*)&scr[c * 68 + li * 4];
      *(float4*)&out[(((size_t)(t * 16 + b) * 384) + m0 + c) * 1024 + n0im + li * 4] = val;
    }
    __syncthreads();
  }
}

extern "C" void kernel_launch(void* const* d_in, const int* in_sizes, int n_in,
                              void* d_out, int out_size, void* d_ws, size_t ws_size,
                              hipStream_t stream) {
  (void)in_sizes; (void)n_in; (void)out_size; (void)ws_size;
  const float* x   = (const float*)d_in[0];
  const float* qw  = (const float*)d_in[1];
  const float* qg  = (const float*)d_in[2];
  const float* qbt = (const float*)d_in[3];
  const float* qm  = (const float*)d_in[4];
  const float* qv  = (const float*)d_in[5];
  const float* kw  = (const float*)d_in[6];
  const float* kg  = (const float*)d_in[7];
  const float* kbt = (const float*)d_in[8];
  const float* km  = (const float*)d_in[9];
  const float* kv  = (const float*)d_in[10];
  const float* vw  = (const float*)d_in[11];
  const float* vg  = (const float*)d_in[12];
  const float* vbt = (const float*)d_in[13];
  const float* vm  = (const float*)d_in[14];
  const float* vv  = (const float*)d_in[15];
  const float* pw  = (const float*)d_in[16];
  const float* pg  = (const float*)d_in[17];
  const float* pbt = (const float*)d_in[18];
  const float* pm  = (const float*)d_in[19];
  const float* pv  = (const float*)d_in[20];
  const float* pbias = (const float*)d_in[21];

  char* ws = (char*)d_ws;
  u8*  xsb   = (u8*)ws;                     // input spikes, packed nibbles (6.3 MB)
  u8*  sp    = (u8*)(ws + 6291456);         // q,k,v spike nibbles (3 x 6.3 MB)
  u8*  xpb   = (u8*)(ws + 25165824);        // q&attn spikes, packed nibbles (6.3 MB)
  u16* Wstk  = (u16*)(ws + 31457280);       // [1152][384] bf16
  u16* Pw    = (u16*)(ws + 32342016);       // [384][384] bf16
  float4* BNP = (float4*)(ws + 32636928);   // [1152]
  float4* PP  = (float4*)(ws + 32655360);   // [384]

  k_convert<<<2310, 256, 0, stream>>>(qw, kw, vw, pw, qg, qbt, qm, qv, kg, kbt, km, kv,
                                      vg, vbt, vm, vv, pg, pbt, pm, pv, pbias,
                                      Wstk, Pw, BNP, PP);
  k_lif_in<<<dim3(16, 6, 16), 256, 0, stream>>>(x, xsb);
  k_qkv<<<dim3(16, 9, 16), 512, 0, stream>>>(Wstk, xsb, BNP, sp);
  k_attn<<<4096, 256, 0, stream>>>(sp, xpb);
  k_proj<<<dim3(16, 3, 16), 512, 0, stream>>>(Pw, xpb, PP, (float*)d_out);
}